// Round 1
// baseline (267.678 us; speedup 1.0000x reference)
//
#include <hip/hip_runtime.h>
#include <math.h>

#define HH 2048
#define WW 4096

// Per-position derived values, matching the reference exactly:
//   Y = d*(r-cy)/fx ; X = d*(c-cx)/fx  (X from UNMASKED depth, uses fx)
//   neg = (Y<=0) -> Z=0, Y=0 ; nan(Z)->0 ; D = 1/Z (inf where Z==0)
//   out-of-bounds (zero padding of the shifted arrays): X=Y=Z=D=0
struct Pix { float X, Y, Z, D; };

__device__ __forceinline__ Pix load_pix(const float* __restrict__ depth,
                                        int r, int c,
                                        float fx, float cx, float cy) {
    Pix p;
    if (r < 0 || r >= HH || c < 0 || c >= WW) {
        p.X = 0.0f; p.Y = 0.0f; p.Z = 0.0f; p.D = 0.0f;
        return p;
    }
    float d  = depth[(size_t)r * WW + c];
    float Yv = d * ((float)r - cy) / fx;
    float Xv = d * ((float)c - cx) / fx;
    float Zv = d;
    if (Yv <= 0.0f) { Zv = 0.0f; Yv = 0.0f; }
    if (isnan(Zv)) Zv = 0.0f;
    p.X = Xv; p.Y = Yv; p.Z = Zv;
    p.D = 1.0f / Zv;          // IEEE: +inf where Zv==0
    return p;
}

__global__ __launch_bounds__(256)
void nim_kernel(const float* __restrict__ depth,
                const float* __restrict__ cam,
                const int*   __restrict__ signf,
                float* __restrict__ out) {
    const int j = blockIdx.x * blockDim.x + threadIdx.x;
    const int i = blockIdx.y;
    if (j >= WW) return;

    const float fx = cam[0];
    const float cx = cam[2];
    const float fy = cam[4];
    const float cy = cam[5];
    const float PI_C = 3.141592657f;

    Pix C  = load_pix(depth, i,     j,     fx, cx, cy);
    Pix U  = load_pix(depth, i - 1, j,     fx, cx, cy);
    Pix Dw = load_pix(depth, i + 1, j,     fx, cx, cy);
    Pix L  = load_pix(depth, i,     j - 1, fx, cx, cy);
    Pix R  = load_pix(depth, i,     j + 1, fx, cx, cy);

    // Gu = D[i,j+1]-D[i,j-1];  Gv = D[i+1,j]-D[i-1,j]
    const float nx_t = (R.D  - L.D) * fx;
    const float ny_t = (Dw.D - U.D) * fy;

    const float phi = atanf(ny_t / nx_t) + PI_C;
    const float a = cosf(phi);
    const float b = sinf(phi);

    // dirs order: up, left, right, down
    Pix N[4];
    N[0] = U; N[1] = L; N[2] = R; N[3] = Dw;

    float nxv[4], nyv[4], nzv[4];
    int npos = 0, nneg = 0;
#pragma unroll
    for (int k = 0; k < 4; ++k) {
        const float Xd = C.X - N[k].X;
        const float Yd = C.Y - N[k].Y;
        const float Zd = C.Z - N[k].Z;
        const float nzi  = -(nx_t * Xd + ny_t * Yd) / Zd;
        const float norm = sqrtf(nx_t * nx_t + ny_t * ny_t + nzi * nzi);
        float vx = nx_t / norm;
        float vy = ny_t / norm;
        float vz = nzi  / norm;
        if (isnan(vx)) vx = 0.0f;
        if (isnan(vy)) vy = 0.0f;
        if (isnan(vz)) vz = 0.0f;
        nxv[k] = vx; nyv[k] = vy; nzv[k] = vz;
        npos += (vz > 0.0f);
        nneg += (vz < 0.0f);
    }

    const int sf = signf[0];
    float sum_nx = 0.0f, sum_ny = 0.0f, sum_nz = 0.0f;
#pragma unroll
    for (int k = 0; k < 4; ++k) {
        float vx = nxv[k], vy = nyv[k], vz = nzv[k];
        if (sf) {
            const bool keep = ((npos >= nneg) && (vz > 0.0f)) ||
                              ((npos <  nneg) && (vz < 0.0f));
            const float fm = keep ? 1.0f : 0.0f;
            vx *= fm; vy *= fm; vz *= fm;
        }
        sum_nx += vx; sum_ny += vy; sum_nz += vz;
    }

    const float theta = atanf((sum_nx * a + sum_ny * b) / sum_nz);
    const float st = sinf(theta);
    float onx = st * a;
    float ony = st * b;
    float onz = cosf(theta);
    if (isnan(onz)) { onx = 0.0f; ony = 0.0f; onz = -1.0f; }
    const float sgn = (ony > 0.0f) ? -1.0f : 1.0f;

    const size_t HW  = (size_t)HH * WW;
    const size_t idx = (size_t)i * WW + j;
    out[idx]          = onx * sgn;
    out[HW + idx]     = ony * sgn;
    out[2 * HW + idx] = onz * sgn;
}

extern "C" void kernel_launch(void* const* d_in, const int* in_sizes, int n_in,
                              void* d_out, int out_size, void* d_ws, size_t ws_size,
                              hipStream_t stream) {
    const float* depth = (const float*)d_in[0];
    const float* cam   = (const float*)d_in[1];
    const int*   signf = (const int*)d_in[2];
    float* out = (float*)d_out;

    dim3 block(256, 1, 1);
    dim3 grid(WW / 256, HH, 1);
    nim_kernel<<<grid, block, 0, stream>>>(depth, cam, signf, out);
}

// Round 2
// 145.759 us; speedup vs baseline: 1.8364x; 1.8364x over previous
//
#include <hip/hip_runtime.h>
#include <math.h>

#define HH 2048
#define WW 4096

__device__ __forceinline__ float rcp_f(float x){ return __builtin_amdgcn_rcpf(x); }
__device__ __forceinline__ float rsq_f(float x){ return __builtin_amdgcn_rsqf(x); }

struct Pix { float X, Y, Z, D; };

// Matches reference per-position values:
//   Y = d*(r-cy)/fx ; X = d*(c-cx)/fx (unmasked depth, fx for both)
//   (Y<=0) -> Y=Z=0 ; nan->0 ; D = 1/Z (+inf where Z==0); OOB pad: all 0
__device__ __forceinline__ Pix load_pix(const float* __restrict__ depth,
                                        int r, int c, float inv_fx,
                                        float cx, float cy){
    Pix p;
    if (r < 0 || r >= HH || c < 0 || c >= WW){
        p.X = 0.f; p.Y = 0.f; p.Z = 0.f; p.D = 0.f; return p;
    }
    float d  = depth[(size_t)r * WW + c];
    float Yv = d * ((float)r - cy) * inv_fx;
    float Xv = d * ((float)c - cx) * inv_fx;
    float Zv = d;
    if (Yv <= 0.f){ Zv = 0.f; Yv = 0.f; }
    if (isnan(Zv)) Zv = 0.f;
    p.X = Xv; p.Y = Yv; p.Z = Zv;
    p.D = rcp_f(Zv);               // v_rcp_f32(0) = +inf, matching 1/0
    return p;
}

__global__ __launch_bounds__(256)
void nim_kernel(const float* __restrict__ depth,
                const float* __restrict__ cam,
                const int*   __restrict__ signf,
                float* __restrict__ out){
    const int j = blockIdx.x * 256 + threadIdx.x;
    const int i = blockIdx.y;
    const size_t HW  = (size_t)HH * WW;
    const size_t idx = (size_t)i * WW + j;

    const float fx = cam[0], cx = cam[2], fy = cam[4], cy = cam[5];

    // For strictly positive depth, any row i <= cy+1 has C or U sign-masked
    // => some D = +inf => every normalized component NaN->0 => sums = 0 =>
    // theta = NaN => reference bad-path output (0,0,-1). Wave-uniform branch.
    if ((float)i <= cy + 1.0f){
        out[idx]        = 0.f;
        out[HW + idx]   = 0.f;
        out[2*HW + idx] = -1.f;
        return;
    }

    const float inv_fx = rcp_f(fx);
    const Pix C  = load_pix(depth, i,     j,     inv_fx, cx, cy);
    const Pix U  = load_pix(depth, i - 1, j,     inv_fx, cx, cy);
    const Pix Dw = load_pix(depth, i + 1, j,     inv_fx, cx, cy);
    const Pix L  = load_pix(depth, i,     j - 1, inv_fx, cx, cy);
    const Pix R  = load_pix(depth, i,     j + 1, inv_fx, cx, cy);

    const float nx = (R.D  - L.D) * fx;
    const float ny = (Dw.D - U.D) * fy;

    // a = cos(atan(ny/nx)+pi) = -|nx|/hypot ; b = sin(...) = -ny*sign(nx)/hypot
    const float r2 = nx*nx + ny*ny;
    const float rr = rsq_f(r2);
    const float rs = copysignf(rr, nx);
    const float a  = -nx * rs;
    const float b  = -ny * rs;

    const Pix Ns[4] = {U, L, R, Dw};   // dirs order: up, left, right, down
    float vxs[4], vys[4], vzs[4];
    int npos = 0, nneg = 0;
#pragma unroll
    for (int k = 0; k < 4; ++k){
        const float Xd  = C.X - Ns[k].X;
        const float Yd  = C.Y - Ns[k].Y;
        const float Zd  = C.Z - Ns[k].Z;
        const float num = -(nx*Xd + ny*Yd);
        const float nzi = num * rcp_f(Zd);      // same ±inf / 0*inf=NaN semantics
        const float s   = r2 + nzi*nzi;
        const float rn  = rsq_f(s);             // 1/norm; rsq(inf)=0, rsq(0)=inf
        float vx = nx * rn, vy = ny * rn, vz = nzi * rn;
        if (isnan(vx)) vx = 0.f;
        if (isnan(vy)) vy = 0.f;
        if (isnan(vz)) vz = 0.f;
        vxs[k] = vx; vys[k] = vy; vzs[k] = vz;
        npos += (vz > 0.f);
        nneg += (vz < 0.f);
    }

    const int sf = signf[0];
    float sx = 0.f, sy = 0.f, sz = 0.f;
#pragma unroll
    for (int k = 0; k < 4; ++k){
        const float vz = vzs[k];
        const bool pm = (npos >= nneg) && (vz > 0.f);
        const bool nm = (npos <  nneg) && (vz < 0.f);
        const float fm = (!sf || pm || nm) ? 1.f : 0.f;
        sx += vxs[k] * fm;
        sy += vys[k] * fm;
        sz += vzs[k] * fm;
    }

    // theta = atan(q): sin = q/sqrt(1+q^2), cos = 1/sqrt(1+q^2)
    const float q  = (sx*a + sy*b) * rcp_f(sz);  // 0*inf=NaN, n*inf=±inf as ref
    const float q2 = q * q;
    const float ct = rsq_f(1.f + q2);
    float st = q * ct;
    if (isinf(q2)) st = copysignf(1.f, q);       // q huge/inf: sin(atan q)=±1

    float onx = st * a, ony = st * b, onz = ct;  // ct NaN iff q NaN == ref bad
    if (isnan(onz)){ onx = 0.f; ony = 0.f; onz = -1.f; }
    const float sgn = (ony > 0.f) ? -1.f : 1.f;

    out[idx]        = onx * sgn;
    out[HW + idx]   = ony * sgn;
    out[2*HW + idx] = onz * sgn;
}

extern "C" void kernel_launch(void* const* d_in, const int* in_sizes, int n_in,
                              void* d_out, int out_size, void* d_ws, size_t ws_size,
                              hipStream_t stream) {
    const float* depth = (const float*)d_in[0];
    const float* cam   = (const float*)d_in[1];
    const int*   signf = (const int*)d_in[2];
    float* out = (float*)d_out;

    dim3 block(256, 1, 1);
    dim3 grid(WW / 256, HH, 1);
    nim_kernel<<<grid, block, 0, stream>>>(depth, cam, signf, out);
}

// Round 3
// 133.953 us; speedup vs baseline: 1.9983x; 1.0881x over previous
//
#include <hip/hip_runtime.h>
#include <math.h>

#define HH 2048
#define WW 4096

__device__ __forceinline__ float rcp_f(float x){ return __builtin_amdgcn_rcpf(x); }
__device__ __forceinline__ float rsq_f(float x){ return __builtin_amdgcn_rsqf(x); }

__global__ __launch_bounds__(256)
void nim_kernel(const float* __restrict__ depth,
                const float* __restrict__ cam,
                const int*   __restrict__ signf,
                float* __restrict__ out)
{
    const int j0 = (blockIdx.x * 256 + threadIdx.x) * 4;  // 4 columns/thread
    const int i  = blockIdx.y;
    const size_t HW  = (size_t)HH * WW;
    const size_t idx = (size_t)i * WW + j0;

    const float cy = cam[5];

    float4* o0 = (float4*)(out + idx);
    float4* o1 = (float4*)(out + HW + idx);
    float4* o2 = (float4*)(out + 2 * HW + idx);

    // Rows i <= cy+1: C or U is sign-masked => some D=+inf => every normalized
    // component NaN->0 => sums 0 => theta NaN => reference bad-path (0,0,-1).
    if ((float)i <= cy + 1.0f){
        *o0 = make_float4(0.f, 0.f, 0.f, 0.f);
        *o1 = make_float4(0.f, 0.f, 0.f, 0.f);
        *o2 = make_float4(-1.f, -1.f, -1.f, -1.f);
        return;
    }

    const float fx = cam[0], cx = cam[2], fy = cam[4];
    const float inv_fx = rcp_f(fx);
    const int   sf = signf[0];

    // Live region: i >= cy+2 -> rows i-1..i+1 have (r-cy) >= 1 -> Y > 0 for
    // all in-bounds pixels (depth > 0), so neg/NaN masks never fire here.
    const float rf_u = ((float)(i - 1) - cy) * inv_fx;
    const float rf_c = ((float)i       - cy) * inv_fx;
    const float rf_d = ((float)(i + 1) - cy) * inv_fx;

    const float4 c4 = *(const float4*)(depth + (size_t)i * WW + j0);
    const float4 u4 = *(const float4*)(depth + (size_t)(i - 1) * WW + j0);
    float4 d4 = make_float4(0.f, 0.f, 0.f, 0.f);
    const bool dvalid = (i + 1 < HH);
    if (dvalid) d4 = *(const float4*)(depth + (size_t)(i + 1) * WW + j0);

    const bool lvalid = (j0 > 0);
    const bool rvalid = (j0 + 4 < WW);
    const float cl = lvalid ? depth[(size_t)i * WW + j0 - 1] : 0.f;
    const float cr = rvalid ? depth[(size_t)i * WW + j0 + 4] : 0.f;

    // column factors for cols j0-1 .. j0+4
    float cf[6];
#pragma unroll
    for (int t = 0; t < 6; ++t)
        cf[t] = ((float)(j0 - 1 + t) - cx) * inv_fx;

    // derived values; zero-padding (OOB) means X=Y=Z=D=0 (pad of shifted maps)
    float dc[6] = {cl, c4.x, c4.y, c4.z, c4.w, cr};
    float Xc[6], Yc[6], Zc[6], Dc[6];
#pragma unroll
    for (int t = 0; t < 6; ++t){
        Xc[t] = dc[t] * cf[t];
        Yc[t] = dc[t] * rf_c;
        Zc[t] = dc[t];
        Dc[t] = rcp_f(dc[t]);
    }
    if (!lvalid){ Xc[0]=0.f; Yc[0]=0.f; Zc[0]=0.f; Dc[0]=0.f; }
    if (!rvalid){ Xc[5]=0.f; Yc[5]=0.f; Zc[5]=0.f; Dc[5]=0.f; }

    const float du[4] = {u4.x, u4.y, u4.z, u4.w};
    const float dd[4] = {d4.x, d4.y, d4.z, d4.w};
    float Xu[4], Yu[4], Zu[4], Du[4], Xd4[4], Yd4[4], Zd4[4], Dd[4];
#pragma unroll
    for (int t = 0; t < 4; ++t){
        Xu[t]  = du[t] * cf[t + 1];
        Yu[t]  = du[t] * rf_u;
        Zu[t]  = du[t];
        Du[t]  = rcp_f(du[t]);
        Xd4[t] = dd[t] * cf[t + 1];
        Yd4[t] = dd[t] * rf_d;
        Zd4[t] = dd[t];
        Dd[t]  = rcp_f(dd[t]);
    }
    if (!dvalid){
#pragma unroll
        for (int t = 0; t < 4; ++t){ Xd4[t]=0.f; Yd4[t]=0.f; Zd4[t]=0.f; Dd[t]=0.f; }
    }

    float ox[4], oy[4], oz[4];
#pragma unroll
    for (int p = 0; p < 4; ++p){
        const float nx = (Dc[p + 2] - Dc[p]) * fx;   // Gu * fx
        const float ny = (Dd[p] - Du[p]) * fy;       // Gv * fy
        const float r2 = nx * nx + ny * ny;
        const float rr = rsq_f(r2);
        const float rs = copysignf(rr, nx);
        // a = cos(atan(ny/nx)+pi) = -|nx|/hypot; b = sin(..) = -ny*sign(nx)/hypot
        const float a = -nx * rs;
        const float b = -ny * rs;

        const float CX = Xc[p + 1], CY = Yc[p + 1], CZ = Zc[p + 1];
        const float NX[4] = {Xu[p], Xc[p], Xc[p + 2], Xd4[p]};  // up,left,right,down
        const float NY[4] = {Yu[p], Yc[p], Yc[p + 2], Yd4[p]};
        const float NZ[4] = {Zu[p], Zc[p], Zc[p + 2], Zd4[p]};

        float vxs[4], vys[4], vzs[4];
        int npos = 0, nneg = 0;
#pragma unroll
        for (int k = 0; k < 4; ++k){
            const float Xd = CX - NX[k];
            const float Yd = CY - NY[k];
            const float w  = CZ - NZ[k];
            const float g  = nx * Xd + ny * Yd;       // nzi = -g/w
            const float arg = (r2 * w) * w + g * g;   // = w^2 * (r2 + nzi^2)
            const float rn  = rsq_f(arg);
            const float h   = fabsf(w) * rn;          // 1/norm
            float vx = nx * h;
            float vy = ny * h;
            float vz = -g * copysignf(rn, w);
            // ref: arg==0 -> norm 0 or NaN chain -> all NaN->0
            //      w==0,g!=0 -> nzi=+-inf -> vz=inf/inf=NaN->0 (vx,vy already 0)
            const bool za = (arg == 0.f);
            if (za){ vx = 0.f; vy = 0.f; }
            if (za || (w == 0.f)) vz = 0.f;
            vxs[k] = vx; vys[k] = vy; vzs[k] = vz;
            npos += (vz > 0.f);
            nneg += (vz < 0.f);
        }

        float sx = 0.f, sy = 0.f, sz = 0.f;
#pragma unroll
        for (int k = 0; k < 4; ++k){
            const float vz = vzs[k];
            const bool keep = !sf ||
                ((npos >= nneg) && (vz > 0.f)) ||
                ((npos <  nneg) && (vz < 0.f));
            const float fm = keep ? 1.f : 0.f;
            sx += vxs[k] * fm;
            sy += vys[k] * fm;
            sz += vzs[k] * fm;
        }

        // theta = atan(q): sin = q*rsq(1+q^2), cos = rsq(1+q^2)
        const float q  = (sx * a + sy * b) * rcp_f(sz);
        const float q2 = q * q;
        const float ct = rsq_f(1.f + q2);
        float st = q * ct;
        if (isinf(q2)) st = copysignf(1.f, q);   // |q| huge: sin(atan q)=+-1

        float onx = st * a, ony = st * b, onz = ct;  // ct NaN iff ref bad path
        if (isnan(onz)){ onx = 0.f; ony = 0.f; onz = -1.f; }
        const float sgn = (ony > 0.f) ? -1.f : 1.f;
        ox[p] = onx * sgn; oy[p] = ony * sgn; oz[p] = onz * sgn;
    }

    *o0 = make_float4(ox[0], ox[1], ox[2], ox[3]);
    *o1 = make_float4(oy[0], oy[1], oy[2], oy[3]);
    *o2 = make_float4(oz[0], oz[1], oz[2], oz[3]);
}

extern "C" void kernel_launch(void* const* d_in, const int* in_sizes, int n_in,
                              void* d_out, int out_size, void* d_ws, size_t ws_size,
                              hipStream_t stream) {
    const float* depth = (const float*)d_in[0];
    const float* cam   = (const float*)d_in[1];
    const int*   signf = (const int*)d_in[2];
    float* out = (float*)d_out;

    dim3 block(256, 1, 1);
    dim3 grid(WW / (256 * 4), HH, 1);
    nim_kernel<<<grid, block, 0, stream>>>(depth, cam, signf, out);
}